// Round 1
// baseline (442.071 us; speedup 1.0000x reference)
//
#include <hip/hip_runtime.h>
#include <hip/hip_bf16.h>

// ---------------------------------------------------------------------------
// DynamicTransformer fused implementation (bf16-MFMA path, fp32 kernel-gen).
//
// Shapes: B=8, DIM=64, H=W=192, HID=128, K=3.
// mean(h) == w_in @ mean_hw(x) + b_in  (proj_in is linear) -> no h roundtrip.
// Tolerance is 2% of ref absmax; bf16 inputs + fp32 MFMA accumulate gives
// ~0.5-0.9% local relative error => safe.
// ---------------------------------------------------------------------------

typedef __bf16 bf16;
typedef __bf16 bf16x4 __attribute__((ext_vector_type(4)));
typedef __bf16 bf16x8 __attribute__((ext_vector_type(8)));
typedef float  f32x4  __attribute__((ext_vector_type(4)));

#define B_   8
#define DIM_ 64
#define HID_ 128
#define HW_  192
#define TO_  6   // output tile edge
#define TH_  8   // h tile edge (halo 1 each side)

// ---------------------------------------------------------------------------
// Kernel 1: per-(b,c) spatial mean of x.  grid = 512 blocks, 256 threads.
// ---------------------------------------------------------------------------
__global__ __launch_bounds__(256) void dt_kmean(const float* __restrict__ x,
                                                float* __restrict__ xmean) {
  const int bc = blockIdx.x;                       // 0..511
  const float4* xp = (const float4*)(x + (size_t)bc * (HW_ * HW_));
  float s = 0.f;
  for (int i = threadIdx.x; i < (HW_ * HW_) / 4; i += 256) {
    float4 v = xp[i];
    s += (v.x + v.y) + (v.z + v.w);
  }
  for (int off = 32; off; off >>= 1) s += __shfl_down(s, off, 64);
  __shared__ float part[4];
  const int lane = threadIdx.x & 63, wv = threadIdx.x >> 6;
  if (lane == 0) part[wv] = s;
  __syncthreads();
  if (threadIdx.x == 0) {
    float tt = (part[0] + part[1]) + (part[2] + part[3]);
    xmean[bc] = tt * (1.f / (HW_ * HW_));
  }
}

// ---------------------------------------------------------------------------
// Kernel 2: kernel generator (exact fp32).  grid = 8 blocks, 128 threads.
// kern[b][c][tap] = wg2 @ relu(wg1 @ (w_in @ xmean[b] + b_in) + bg1) + bg2
// ---------------------------------------------------------------------------
__global__ __launch_bounds__(128) void dt_kgen(
    const float* __restrict__ xmean, const float* __restrict__ w_in,
    const float* __restrict__ b_in, const float* __restrict__ wg1,
    const float* __restrict__ bg1, const float* __restrict__ wg2,
    const float* __restrict__ bg2, float* __restrict__ kern) {
  const int b = blockIdx.x, t = threadIdx.x;
  __shared__ float xm[DIM_], hm[HID_], g[HID_];
  if (t < DIM_) xm[t] = xmean[b * DIM_ + t];
  __syncthreads();
  {
    float a = b_in[t];
    const float* w = w_in + t * DIM_;
    for (int c = 0; c < DIM_; ++c) a += w[c] * xm[c];
    hm[t] = a;
  }
  __syncthreads();
  {
    float a = bg1[t];
    const float* w = wg1 + t * HID_;
    for (int c = 0; c < HID_; ++c) a += w[c] * hm[c];
    g[t] = a > 0.f ? a : 0.f;
  }
  __syncthreads();
  for (int idx = t; idx < HID_ * 9; idx += 128) {
    float a = bg2[idx];
    const float* w = wg2 + idx * HID_;
    for (int c = 0; c < HID_; ++c) a += w[c] * g[c];
    kern[b * (HID_ * 9) + idx] = a;
  }
}

// ---------------------------------------------------------------------------
// Kernel 3: fused proj_in (MFMA) -> depthwise 3x3 (fp32) -> leaky -> proj_out
// (MFMA).  Tile: 6x6 out px, 8x8 h px.  grid = (32,32,8), 256 threads.
//
// LDS map (50688 B total, 3 blocks/CU):
//   [0,12288)      XY: phase01 x_s [64p][64c] bf16 swizzled;
//                      phase23 y_s [48p][128o] bf16 swizzled (A-operand)
//   [12288,28672)  W : phase01 w_in  [128o][64c] bf16 swizzled (B-operand)
//                      phase23 w_out [64j][128o] bf16 swizzled (B-operand)
//   [28672,46080)  H : h_s [128o][pitch 68] bf16
//   [46080,50688)  K : dyn kernels [128][9] f32
// XOR swizzle on 16B chunks breaks the p-major bank aliasing.
// ---------------------------------------------------------------------------
__global__ __launch_bounds__(256, 3) void dt_kmain(
    const float* __restrict__ x, const float* __restrict__ w_in,
    const float* __restrict__ b_in, const float* __restrict__ w_out,
    const float* __restrict__ b_out, const float* __restrict__ kernbuf,
    float* __restrict__ out) {
  __shared__ __attribute__((aligned(16))) char smem[50688];
  bf16* xs  = (bf16*)(smem);            // [p*64 + c'] (c' swizzled)
  bf16* ysb = (bf16*)(smem);            // [p*128 + o'] (o' swizzled)
  bf16* wbs = (bf16*)(smem + 12288);    // [o*64 + c']
  bf16* wos = (bf16*)(smem + 12288);    // [j*128 + o']
  bf16* hs  = (bf16*)(smem + 28672);    // [o*68 + p]
  float* ks = (float*)(smem + 46080);   // [o*9 + tap]

  const int t  = threadIdx.x;
  const int bb = blockIdx.z, tyb = blockIdx.y, txb = blockIdx.x;
  const int y0 = tyb * TO_ - 1, x0 = txb * TO_ - 1;   // h-tile origin

  // ---- Phase 0: stage x tile, w_in, dyn kernels -------------------------
  // x: 512 rows of (c, dy); each row = 8 px along x.  Transpose into [p][c].
  for (int i = 0; i < 2; ++i) {
    const int rid = t * 2 + i;
    const int c = rid >> 3, dy = rid & 7;
    const int yy = y0 + dy;
    const bool yok = (unsigned)yy < (unsigned)HW_;
    const float* xrow = x + (((size_t)bb * DIM_ + c) * HW_ + yy) * HW_;
    const int q = c >> 3, j = c & 7;
#pragma unroll
    for (int dx = 0; dx < TH_; ++dx) {
      const int xx = x0 + dx;
      const float v = (yok && (unsigned)xx < (unsigned)HW_) ? xrow[xx] : 0.f;
      const int p = dy * 8 + dx;
      xs[p * 64 + ((q ^ (p & 7)) << 3) + j] = (bf16)v;
    }
  }
  // w_in (128x64 f32 row-major) -> wbs[o][c] bf16 swizzled. 32 f32/thread.
  {
    const int o = t >> 1, cb = (t & 1) << 5;   // c base 0 or 32
    const float4* wp4 = (const float4*)(w_in + o * DIM_ + cb);
#pragma unroll
    for (int q8 = 0; q8 < 4; ++q8) {
      float4 a = wp4[q8 * 2], b2 = wp4[q8 * 2 + 1];
      bf16x8 pk = {(bf16)a.x, (bf16)a.y, (bf16)a.z, (bf16)a.w,
                   (bf16)b2.x, (bf16)b2.y, (bf16)b2.z, (bf16)b2.w};
      const int q = (cb >> 3) + q8;
      *(bf16x8*)(wbs + o * 64 + ((q ^ (o & 7)) << 3)) = pk;
    }
  }
  for (int i = t; i < HID_ * 9; i += 256) ks[i] = kernbuf[bb * (HID_ * 9) + i];
  __syncthreads();

  const int wv = t >> 6, lane = t & 63, quad = lane >> 4, lr = lane & 15;

  // ---- Phase 1: h[64px][128o] = x @ w_in  (MFMA 16x16x32 bf16) ----------
  // wave wv owns n-tiles {2wv, 2wv+1}; all 4 m-tiles.
  {
    f32x4 acc[4][2];
#pragma unroll
    for (int m = 0; m < 4; ++m)
#pragma unroll
      for (int n = 0; n < 2; ++n) acc[m][n] = 0.f;

#pragma unroll
    for (int kh = 0; kh < 2; ++kh) {
      const int ql = 4 * kh + quad;
      bf16x8 af[4];
#pragma unroll
      for (int m = 0; m < 4; ++m) {
        const int p = 16 * m + lr;
        af[m] = *(const bf16x8*)(xs + p * 64 + ((ql ^ (p & 7)) << 3));
      }
#pragma unroll
      for (int n = 0; n < 2; ++n) {
        const int o = 16 * (2 * wv + n) + lr;
        bf16x8 bfrag = *(const bf16x8*)(wbs + o * 64 + ((ql ^ (o & 7)) << 3));
#pragma unroll
        for (int m = 0; m < 4; ++m)
          acc[m][n] = __builtin_amdgcn_mfma_f32_16x16x32_bf16(af[m], bfrag,
                                                              acc[m][n], 0, 0, 0);
      }
    }
    // epilogue: + b_in, convert bf16, write hs[o][p] (b64 packed)
#pragma unroll
    for (int n = 0; n < 2; ++n) {
      const int o = 16 * (2 * wv + n) + lr;
      const float bi = b_in[o];
#pragma unroll
      for (int m = 0; m < 4; ++m) {
        const int p0 = 16 * m + 4 * quad;
        bf16x4 pk = {(bf16)(acc[m][n][0] + bi), (bf16)(acc[m][n][1] + bi),
                     (bf16)(acc[m][n][2] + bi), (bf16)(acc[m][n][3] + bi)};
        *(bf16x4*)(hs + o * 68 + p0) = pk;
      }
    }
  }
  __syncthreads();   // x_s, wbs dead after this point

  // ---- Phase 2a: stage w_out (64x128 f32) -> wos[j][o] bf16 swizzled ----
  {
    const int jj = t >> 2, ob = (t & 3) << 5;
    const float4* wp4 = (const float4*)(w_out + jj * HID_ + ob);
#pragma unroll
    for (int q8 = 0; q8 < 4; ++q8) {
      float4 a = wp4[q8 * 2], b2 = wp4[q8 * 2 + 1];
      bf16x8 pk = {(bf16)a.x, (bf16)a.y, (bf16)a.z, (bf16)a.w,
                   (bf16)b2.x, (bf16)b2.y, (bf16)b2.z, (bf16)b2.w};
      const int q = (ob >> 3) + q8;
      *(bf16x8*)(wos + jj * 128 + ((q ^ (jj & 15)) << 3)) = pk;
    }
  }
  // ---- Phase 2b: depthwise 3x3 (fp32) + leaky -> y_s [p][o] bf16 --------
  {
    const int o = t & 127, half = t >> 7;    // half: px rows 3h..3h+2
    float kk[9];
#pragma unroll
    for (int i = 0; i < 9; ++i) kk[i] = ks[o * 9 + i];
    float hh[5][8];
#pragma unroll
    for (int r = 0; r < 5; ++r) {
      const int dy = 3 * half + r;
      bf16x4 a  = *(const bf16x4*)(hs + o * 68 + dy * 8);
      bf16x4 b2 = *(const bf16x4*)(hs + o * 68 + dy * 8 + 4);
#pragma unroll
      for (int cc = 0; cc < 4; ++cc) {
        hh[r][cc]     = (float)a[cc];
        hh[r][4 + cc] = (float)b2[cc];
      }
    }
    const int oq = o >> 3, oj = o & 7;
#pragma unroll
    for (int py = 0; py < 3; ++py) {
#pragma unroll
      for (int px = 0; px < TO_; ++px) {
        float v = 0.f;
#pragma unroll
        for (int dy2 = 0; dy2 < 3; ++dy2)
#pragma unroll
          for (int dx2 = 0; dx2 < 3; ++dx2)
            v += kk[dy2 * 3 + dx2] * hh[py + dy2][px + dx2];
        v = v > 0.f ? v : 0.1f * v;                   // LeakyReLU(0.1)
        const int p = (3 * half + py) * TO_ + px;     // 0..35
        ysb[p * 128 + (((oq ^ (p & 7)) << 3) | oj)] = (bf16)v;
      }
    }
  }
  __syncthreads();

  // ---- Phase 3: out[36px][64j] = y @ w_out^T (MFMA) + b_out -------------
  // wave wv owns n-tile wv (j = 16wv+lr); m-tiles 0..2 (px padded to 48,
  // garbage rows >=36 only pollute D rows >=36 which are never stored).
  {
    f32x4 acc3[3];
#pragma unroll
    for (int m = 0; m < 3; ++m) acc3[m] = 0.f;
    const int jj = 16 * wv + lr;
#pragma unroll
    for (int ks2 = 0; ks2 < 4; ++ks2) {
      const int ql = 4 * ks2 + quad;   // 0..15
      bf16x8 bfrag =
          *(const bf16x8*)(wos + jj * 128 + ((ql ^ (jj & 15)) << 3));
#pragma unroll
      for (int m = 0; m < 3; ++m) {
        const int p = 16 * m + lr;
        bf16x8 afrag =
            *(const bf16x8*)(ysb + p * 128 + (((ql ^ (p & 7)) & 15) << 3));
        acc3[m] = __builtin_amdgcn_mfma_f32_16x16x32_bf16(afrag, bfrag,
                                                          acc3[m], 0, 0, 0);
      }
    }
    const float bo = b_out[jj];
    float* obase = out + ((size_t)bb * DIM_ + jj) * (HW_ * HW_);
#pragma unroll
    for (int m = 0; m < 3; ++m) {
#pragma unroll
      for (int r = 0; r < 4; ++r) {
        const int p = 16 * m + 4 * quad + r;
        if (p < TO_ * TO_) {
          const int oy = p / TO_, ox = p - oy * TO_;
          obase[(size_t)(y0 + 1 + oy) * HW_ + (x0 + 1 + ox)] = acc3[m][r] + bo;
        }
      }
    }
  }
}

// ---------------------------------------------------------------------------
extern "C" void kernel_launch(void* const* d_in, const int* in_sizes, int n_in,
                              void* d_out, int out_size, void* d_ws,
                              size_t ws_size, hipStream_t stream) {
  const float* x     = (const float*)d_in[0];
  const float* w_in  = (const float*)d_in[1];
  const float* b_in  = (const float*)d_in[2];
  const float* wg1   = (const float*)d_in[3];
  const float* bg1   = (const float*)d_in[4];
  const float* wg2   = (const float*)d_in[5];
  const float* bg2   = (const float*)d_in[6];
  const float* w_out = (const float*)d_in[7];
  const float* b_out = (const float*)d_in[8];
  float* out = (float*)d_out;

  float* xmean = (float*)d_ws;            // 512 f32
  float* kern  = xmean + B_ * DIM_;       // 8*1152 f32

  dt_kmean<<<dim3(B_ * DIM_), dim3(256), 0, stream>>>(x, xmean);
  dt_kgen<<<dim3(B_), dim3(128), 0, stream>>>(xmean, w_in, b_in, wg1, bg1, wg2,
                                              bg2, kern);
  dt_kmain<<<dim3(HW_ / TO_, HW_ / TO_, B_), dim3(256), 0, stream>>>(
      x, w_in, b_in, w_out, b_out, kern, out);
}